// Round 11
// baseline (210.271 us; speedup 1.0000x reference)
//
#include <hip/hip_runtime.h>
#include <hip/hip_bf16.h>
#include <math.h>

#define NB 512
#define NS 200
#define NH 256
#define TILE_S 32
#define LDSPAD 8
#define LDW (NH + LDSPAD)        // 264 f16 row stride
#define WS_STRIDE 257            // per (b,half): [Z, pooled[256]] (no max needed)
#define NPART (NB * 2)

// ws float-offset layout
#define OFF_PART 0                                 // 1024*257 floats
#define OFF_L    (NPART * WS_STRIDE)               // l: 512*256 floats
#define OFF_UB   (OFF_L + NB * NH)                 // U-fp16 swizzled (32768 floats)
#define WS_FLOATS_PRE  (OFF_UB + (NH * NH) / 2)    // 1.708 MB (same as R2's grant)

typedef _Float16 f16x8 __attribute__((ext_vector_type(8)));
typedef float    f32x4 __attribute__((ext_vector_type(4)));

// DPP-based add within each 16-lane row (VALU, not LDS port).
template<int CTRL>
__device__ __forceinline__ float dpp_xadd(float v) {
  return v + __int_as_float(
      __builtin_amdgcn_update_dpp(0, __float_as_int(v), CTRL, 0xf, 0xf, true));
}
// full 16-lane sum: quad_perm[1,0,3,2]=0xB1, quad_perm[2,3,0,1]=0x4E,
// row_ror:4=0x124, row_ror:8=0x128  (HW-verified in R2)
__device__ __forceinline__ float row16_sum(float v) {
  v = dpp_xadd<0xB1>(v);
  v = dpp_xadd<0x4E>(v);
  v = dpp_xadd<0x124>(v);
  v = dpp_xadd<0x128>(v);
  return v;
}

// ---------------- Kernel 0: precompute l = lastm@W^T (fp32) and swizzled fp16 U ----
__global__ __launch_bounds__(256)
void precompute(const float* __restrict__ lastm, const float* __restrict__ W,
                const float* __restrict__ U,
                float* __restrict__ l_ws, _Float16* __restrict__ Uswz)
{
  const int t = threadIdx.x;
  if (blockIdx.x < NB) {
    const int b = blockIdx.x;
    __shared__ float lm_sm[NH];
    lm_sm[t] = lastm[(size_t)b * NH + t];
    __syncthreads();
    const float4* wrow = (const float4*)(W + (size_t)t * NH);
    const float4* lrow = (const float4*)lm_sm;
    float a0 = 0.f, a1 = 0.f, a2 = 0.f, a3 = 0.f;
#pragma unroll 8
    for (int i = 0; i < NH / 4; ++i) {
      float4 w4 = wrow[i];
      float4 m4 = lrow[i];
      a0 = fmaf(w4.x, m4.x, a0);
      a1 = fmaf(w4.y, m4.y, a1);
      a2 = fmaf(w4.z, m4.z, a2);
      a3 = fmaf(w4.w, m4.w, a3);
    }
    l_ws[(size_t)b * NH + t] = (a0 + a1) + (a2 + a3);
  } else {
    const int id    = (blockIdx.x - NB) * 256 + t;   // 8192 frags
    const int n_blk = id >> 9;
    const int kk    = (id >> 6) & 7;
    const int lane  = id & 63;
    const int row   = n_blk * 16 + (lane & 15);
    const int col   = kk * 32 + (lane >> 4) * 8;
    const float4* s = (const float4*)(U + (size_t)row * NH + col);
    const float4 a = s[0], c = s[1];
    f16x8 pk;
    pk[0] = (_Float16)a.x; pk[1] = (_Float16)a.y;
    pk[2] = (_Float16)a.z; pk[3] = (_Float16)a.w;
    pk[4] = (_Float16)c.x; pk[5] = (_Float16)c.y;
    pk[6] = (_Float16)c.z; pk[7] = (_Float16)c.w;
    *(f16x8*)(Uswz + (size_t)id * 8) = pk;
  }
}

#define CVT_HL(idx, val) { const float x_ = (val); const _Float16 h_ = (_Float16)x_; \
                           ph[idx] = h_; pl[idx] = (_Float16)(x_ - (float)h_); }

// ---------------- Kernel A: partial attention pool over an S-half -------------
// grid 1024 = (b, half): half 0 -> s in [0,96) (3 tiles), half 1 -> [96,200) (4).
// 512 threads = 8 waves x 32 n-cols. __launch_bounds__(512, 3): min-blocks-per-CU
// semantics (measured R2-R6); 3 blocks/CU -> 6 waves/SIMD -> VGPR cap 80 = R10's
// exact usage. LDS trimmed to ~52 KB (x3 = 157 <= 160 KB) by SINGLE-buffering
// lo_sm: lo is read only by MFMA(t) (completes at bar1) and written by staging
// between bar1/bar2 — no overlap. hi stays double-buffered (pooled reads it
// after bar2). No-max softmax (R10; partials merge by plain addition).
// R8 lesson: hi/lo dual MFMA stream is the latency-hiding work — keep it.
template<bool PRE>
__global__ __launch_bounds__(512, 3)
void fused_part(const float* __restrict__ mem,    // [B,S,H]
                const float* __restrict__ lastm,  // [B,H]
                const float* __restrict__ U,      // [H,H] fp32 (fallback)
                const float* __restrict__ W,      // [H,H] (fallback)
                const float* __restrict__ V,      // [H]
                const float* __restrict__ l_ws,   // [B,H] (PRE)
                const _Float16* __restrict__ Uswz,// swizzled fp16 U (PRE)
                float* __restrict__ part)         // [NPART, WS_STRIDE]
{
  const int b    = blockIdx.x >> 1;
  const int half = blockIdx.x & 1;
  const int s_begin = half ? 96 : 0;
  const int s_end   = half ? NS : 96;
  const int ntiles  = half ? 4 : 3;

  const int t     = threadIdx.x;   // 0..511
  const int wave  = t >> 6;        // 0..7: owns n-cols [wave*32, wave*32+32)
  const int lane  = t & 63;
  const int m16   = lane & 15;
  const int quad  = lane >> 4;
  const int g     = t >> 5;        // 0..15: pooled row-pair {2g, 2g+1}
  const int hblk  = (t & 31) * 8;  // pooled: 8 h-cols

  __shared__ __align__(16) _Float16 hi_sm[2][TILE_S][LDW];  // 33.8 KB (dbuf)
  __shared__ __align__(16) _Float16 lo_sm[TILE_S][LDW];     // 16.9 KB (single)
  __shared__ float swave_sm[8][TILE_S];
  __shared__ float e_sm[TILE_S];

  // per-thread l/V for this wave's 2 n-fragments
  float l_reg[2], v_reg[2];
  if constexpr (!PRE) {
    __shared__ float l_sm[NH];
    __shared__ float lm_sm[NH];
    if (t < NH) lm_sm[t] = lastm[(size_t)b * NH + t];
    __syncthreads();
    if (t < NH) {
      const float4* wrow = (const float4*)(W + (size_t)t * NH);
      const float4* lrow = (const float4*)lm_sm;
      float a0 = 0.f, a1 = 0.f, a2 = 0.f, a3 = 0.f;
#pragma unroll 8
      for (int i = 0; i < NH / 4; ++i) {
        float4 w4 = wrow[i];
        float4 m4 = lrow[i];
        a0 = fmaf(w4.x, m4.x, a0);
        a1 = fmaf(w4.y, m4.y, a1);
        a2 = fmaf(w4.z, m4.z, a2);
        a3 = fmaf(w4.w, m4.w, a3);
      }
      l_sm[t] = (a0 + a1) + (a2 + a3);
    }
    __syncthreads();
#pragma unroll
    for (int nf = 0; nf < 2; ++nf)
      l_reg[nf] = l_sm[wave * 32 + nf * 16 + m16];
  } else {
#pragma unroll
    for (int nf = 0; nf < 2; ++nf)
      l_reg[nf] = l_ws[(size_t)b * NH + wave * 32 + nf * 16 + m16];
  }
#pragma unroll
  for (int nf = 0; nf < 2; ++nf)
    v_reg[nf] = V[wave * 32 + nf * 16 + m16];
  const float vsum  = v_reg[0] + v_reg[1];
  const float vm2_0 = -2.f * v_reg[0];
  const float vm2_1 = -2.f * v_reg[1];

  // ---- U B-fragments in registers for the whole kernel: 2 nf x 8 kk = 64 VGPR ----
  f16x8 u_frag[2][8];
  if constexpr (PRE) {
    const _Float16* uw = Uswz + ((size_t)(wave * 2 * 8 * 64) + lane) * 8;
#pragma unroll
    for (int nf = 0; nf < 2; ++nf)
#pragma unroll
      for (int kk = 0; kk < 8; ++kk)
        u_frag[nf][kk] = *(const f16x8*)(uw + (size_t)((nf * 8 + kk) << 9));
  } else {
#pragma unroll
    for (int nf = 0; nf < 2; ++nf) {
      const int n = wave * 32 + nf * 16 + m16;
      const float* urow = U + (size_t)n * NH;
#pragma unroll
      for (int kk = 0; kk < 8; ++kk) {
        const float4 lo = *(const float4*)(urow + kk * 32 + quad * 8);
        const float4 hi = *(const float4*)(urow + kk * 32 + quad * 8 + 4);
        f16x8 f;
        f[0] = (_Float16)lo.x; f[1] = (_Float16)lo.y;
        f[2] = (_Float16)lo.z; f[3] = (_Float16)lo.w;
        f[4] = (_Float16)hi.x; f[5] = (_Float16)hi.y;
        f[6] = (_Float16)hi.z; f[7] = (_Float16)hi.w;
        u_frag[nf][kk] = f;
      }
    }
  }

  // ---- prologue: stage tile 0 (full 32 rows for both halves); issue L(1) ----
  float4 q00, q01, q10, q11;   // pending-tile prefetch (persists across iterations)
  {
    const float4* src4 = (const float4*)(mem + ((size_t)b * NS + s_begin) * NH);
    const int f0 = t, f1 = 512 + t;
    const float4 a0 = src4[f0 * 2], a1 = src4[f0 * 2 + 1];
    const float4 b0 = src4[f1 * 2], b1 = src4[f1 * 2 + 1];
    {
      f16x8 ph, pl;
      CVT_HL(0, a0.x) CVT_HL(1, a0.y) CVT_HL(2, a0.z) CVT_HL(3, a0.w)
      CVT_HL(4, a1.x) CVT_HL(5, a1.y) CVT_HL(6, a1.z) CVT_HL(7, a1.w)
      *(f16x8*)&hi_sm[0][f0 >> 5][(f0 & 31) * 8] = ph;
      *(f16x8*)&lo_sm[f0 >> 5][(f0 & 31) * 8] = pl;
    }
    {
      f16x8 ph, pl;
      CVT_HL(0, b0.x) CVT_HL(1, b0.y) CVT_HL(2, b0.z) CVT_HL(3, b0.w)
      CVT_HL(4, b1.x) CVT_HL(5, b1.y) CVT_HL(6, b1.z) CVT_HL(7, b1.w)
      *(f16x8*)&hi_sm[0][f1 >> 5][(f1 & 31) * 8] = ph;
      *(f16x8*)&lo_sm[f1 >> 5][(f1 & 31) * 8] = pl;
    }
    // issue L(1) — second tile of each half is always full (32 rows)
    const float4* nsrc = (const float4*)(mem + ((size_t)b * NS + s_begin + TILE_S) * NH);
    q00 = nsrc[t * 2];         q01 = nsrc[t * 2 + 1];
    q10 = nsrc[(512 + t) * 2]; q11 = nsrc[(512 + t) * 2 + 1];
  }
  __syncthreads();

  float z_local = 0.f;   // lanes t<32: running sum of e over this lane's rows
  float pooledv[8];
#pragma unroll
  for (int j = 0; j < 8; ++j) pooledv[j] = 0.f;

  for (int tile = 0; tile < ntiles; ++tile) {
    const int cur = tile & 1;
    const int nxt = cur ^ 1;
    const int s0  = s_begin + tile * TILE_S;
    const int rows   = min(TILE_S, s_end - s0);
    const int rows_w = (tile + 1 < ntiles) ? min(TILE_S, s_end - (s0 + TILE_S)) : 0;
    const int rows_i = (tile + 2 < ntiles) ? min(TILE_S, s_end - (s0 + 2 * TILE_S)) : 0;

    // ---- MFMA: 32 rows x 32 n-cols per wave; hi+lo into same acc ----
    f32x4 acc[2][2];
    const f32x4 fzero = {0.f, 0.f, 0.f, 0.f};
#pragma unroll
    for (int mt = 0; mt < 2; ++mt)
#pragma unroll
      for (int nf = 0; nf < 2; ++nf)
        acc[mt][nf] = fzero;

#pragma unroll
    for (int kk = 0; kk < 8; ++kk) {
      const int c = kk * 32 + quad * 8;
      f16x8 a0h = *(const f16x8*)&hi_sm[cur][m16][c];
      f16x8 a1h = *(const f16x8*)&hi_sm[cur][16 + m16][c];
      f16x8 a0l = *(const f16x8*)&lo_sm[m16][c];
      f16x8 a1l = *(const f16x8*)&lo_sm[16 + m16][c];
#pragma unroll
      for (int nf = 0; nf < 2; ++nf) {
        acc[0][nf] = __builtin_amdgcn_mfma_f32_16x16x32_f16(a0h, u_frag[nf][kk], acc[0][nf], 0, 0, 0);
        acc[1][nf] = __builtin_amdgcn_mfma_f32_16x16x32_f16(a1h, u_frag[nf][kk], acc[1][nf], 0, 0, 0);
        acc[0][nf] = __builtin_amdgcn_mfma_f32_16x16x32_f16(a0l, u_frag[nf][kk], acc[0][nf], 0, 0, 0);
        acc[1][nf] = __builtin_amdgcn_mfma_f32_16x16x32_f16(a1l, u_frag[nf][kk], acc[1][nf], 0, 0, 0);
      }
    }

    // ---- p = vsum + sum_nf (-2 v[nf]) / (e^{2x}+1) (tanh identity), DPP n-reduce ----
#pragma unroll
    for (int mt = 0; mt < 2; ++mt) {
#pragma unroll
      for (int reg = 0; reg < 4; ++reg) {
        const float x0 = acc[mt][0][reg] + l_reg[0];
        const float x1 = acc[mt][1][reg] + l_reg[1];
        const float e0 = __expf(x0 + x0);
        const float e1 = __expf(x1 + x1);
        float s = vsum;
        s += __fdividef(vm2_0, e0 + 1.f);
        s += __fdividef(vm2_1, e1 + 1.f);
        s = row16_sum(s);
        if (m16 == 0)
          swave_sm[wave][mt * 16 + quad * 4 + reg] = s;
      }
    }
    __syncthreads();  // bar1: swave ready; MFMA reads of hi[cur]/lo done

    // ---- lanes 0..31: e = exp(score) directly (no max, no shuffle chains) ----
    if (t < TILE_S) {
      float s = swave_sm[0][t];
#pragma unroll
      for (int w = 1; w < 8; ++w) s += swave_sm[w][t];
      const float e = (t < rows) ? __expf(s) : 0.f;
      e_sm[t] = e;
      z_local += e;
    }

    // ---- all waves: write pending tile (t+1) from q regs; lo single-buffered ----
    if ((t >> 5) < rows_w) {
      f16x8 ph, pl;
      CVT_HL(0, q00.x) CVT_HL(1, q00.y) CVT_HL(2, q00.z) CVT_HL(3, q00.w)
      CVT_HL(4, q01.x) CVT_HL(5, q01.y) CVT_HL(6, q01.z) CVT_HL(7, q01.w)
      *(f16x8*)&hi_sm[nxt][t >> 5][(t & 31) * 8] = ph;
      *(f16x8*)&lo_sm[t >> 5][(t & 31) * 8] = pl;
    }
    if (16 + (t >> 5) < rows_w) {
      f16x8 ph, pl;
      CVT_HL(0, q10.x) CVT_HL(1, q10.y) CVT_HL(2, q10.z) CVT_HL(3, q10.w)
      CVT_HL(4, q11.x) CVT_HL(5, q11.y) CVT_HL(6, q11.z) CVT_HL(7, q11.w)
      *(f16x8*)&hi_sm[nxt][16 + (t >> 5)][(t & 31) * 8] = ph;
      *(f16x8*)&lo_sm[16 + (t >> 5)][(t & 31) * 8] = pl;
    }

    // ---- issue loads for tile t+2 (consumed next tile) ----
    if (rows_i > 0) {
      const float4* nsrc = (const float4*)(mem + ((size_t)b * NS + s0 + 2 * TILE_S) * NH);
      if ((t >> 5) < rows_i)      { q00 = nsrc[t * 2];         q01 = nsrc[t * 2 + 1]; }
      if (16 + (t >> 5) < rows_i) { q10 = nsrc[(512 + t) * 2]; q11 = nsrc[(512 + t) * 2 + 1]; }
    }
    __syncthreads();  // bar2: e_sm ready; next tile staged

    // ---- pooled: thread owns 8 h-cols x 2 rows of hi_sm[cur]; no rescale.
    //      NO bar after: staging(t+1) writes hi[cur] only after bar1(t+1). ----
    const float e0 = e_sm[2 * g];
    const float e1 = e_sm[2 * g + 1];
    const f16x8 r0 = *(const f16x8*)&hi_sm[cur][2 * g][hblk];
    const f16x8 r1 = *(const f16x8*)&hi_sm[cur][2 * g + 1][hblk];
#pragma unroll
    for (int j = 0; j < 8; ++j)
      pooledv[j] = fmaf(e0, (float)r0[j], fmaf(e1, (float)r1[j], pooledv[j]));
  }
  __syncthreads();  // final pooled reads done before scratch reuse

  // ---- epilogue: Z reduce (wave0), combine 16 replicas, write partials ----
  float* base    = part + (size_t)blockIdx.x * WS_STRIDE;
  float* scratch = (float*)&hi_sm[0][0][0];   // 16 x 264 f32 = 16896 B, fits
  if (t < TILE_S) {
    float z = z_local;
#pragma unroll
    for (int off = 1; off < 32; off <<= 1)
      z += __shfl_xor(z, off);
    if (t == 0) base[0] = z;
  }
  {
    f32x4 lo4 = {pooledv[0], pooledv[1], pooledv[2], pooledv[3]};
    f32x4 hi4 = {pooledv[4], pooledv[5], pooledv[6], pooledv[7]};
    *(f32x4*)&scratch[g * 264 + hblk]     = lo4;
    *(f32x4*)&scratch[g * 264 + hblk + 4] = hi4;
  }
  __syncthreads();
  if (t < NH) {
    float p = 0.f;
#pragma unroll
    for (int r = 0; r < 16; ++r)
      p += scratch[r * 264 + t];
    base[1 + t] = p;     // unnormalized; merge kernel divides by Z0+Z1
  }
}

// ---------------- Kernel B: merge halves (plain adds) + MetaW projection ------
__global__ __launch_bounds__(256)
void merge_project(const float* __restrict__ part,
                   const float* __restrict__ MetaW,  // [4,H]
                   const float* __restrict__ Metab,  // [4]
                   float* __restrict__ out)          // [B,4]
{
  const int b    = blockIdx.x;
  const int t    = threadIdx.x;
  const int wave = t >> 6;
  const int lane = t & 63;

  __shared__ float pooled_sm[NH];

  const float* b0 = part + (size_t)(b * 2)     * WS_STRIDE;
  const float* b1 = part + (size_t)(b * 2 + 1) * WS_STRIDE;
  const float Zi = 1.f / (b0[0] + b1[0]);
  pooled_sm[t] = (b0[1 + t] + b1[1 + t]) * Zi;
  __syncthreads();

  float s = 0.f;
#pragma unroll
  for (int i = 0; i < 4; ++i) {
    const int h = i * 64 + lane;
    s = fmaf(pooled_sm[h], MetaW[(size_t)wave * NH + h], s);
  }
#pragma unroll
  for (int off = 32; off > 0; off >>= 1)
    s += __shfl_down(s, off);
  if (lane == 0)
    out[b * 4 + wave] = s + Metab[wave];
}

extern "C" void kernel_launch(void* const* d_in, const int* in_sizes, int n_in,
                              void* d_out, int out_size, void* d_ws, size_t ws_size,
                              hipStream_t stream) {
  const float* mem   = (const float*)d_in[0];
  const float* lastm = (const float*)d_in[1];
  const float* U     = (const float*)d_in[2];
  const float* W     = (const float*)d_in[3];
  const float* V     = (const float*)d_in[4];
  const float* MetaW = (const float*)d_in[5];
  const float* Metab = (const float*)d_in[6];
  float* out = (float*)d_out;
  float* ws  = (float*)d_ws;

  float* part = ws + OFF_PART;

  if (ws_size >= (size_t)WS_FLOATS_PRE * sizeof(float)) {
    float*    l_ws = ws + OFF_L;
    _Float16* Uswz = (_Float16*)(ws + OFF_UB);
    hipLaunchKernelGGL(precompute, dim3(NB + 32), dim3(256), 0, stream,
                       lastm, W, U, l_ws, Uswz);
    hipLaunchKernelGGL(fused_part<true>, dim3(NPART), dim3(512), 0, stream,
                       mem, lastm, U, W, V, l_ws, Uswz, part);
  } else {
    hipLaunchKernelGGL(fused_part<false>, dim3(NPART), dim3(512), 0, stream,
                       mem, lastm, U, W, V, (const float*)nullptr, (const _Float16*)nullptr,
                       part);
  }
  hipLaunchKernelGGL(merge_project, dim3(NB), dim3(256), 0, stream,
                     part, MetaW, Metab, out);
}

// Round 12
// 193.680 us; speedup vs baseline: 1.0857x; 1.0857x over previous
//
#include <hip/hip_runtime.h>
#include <hip/hip_bf16.h>
#include <math.h>

#define NB 512
#define NS 200
#define NH 256
#define TILE_S 32
#define LDSPAD 8
#define LDW (NH + LDSPAD)        // 264 f16 row stride

// ws float-offset layout (l + swizzled fp16 U only)
#define OFF_L    0                                 // l: 512*256 floats
#define OFF_UB   (NB * NH)                         // U-fp16 swizzled (32768 floats)
#define WS_FLOATS_PRE  (OFF_UB + (NH * NH) / 2)    // 655 KB

typedef _Float16 f16x8 __attribute__((ext_vector_type(8)));
typedef float    f32x4 __attribute__((ext_vector_type(4)));

// DPP-based add within each 16-lane row (VALU, not LDS port).
template<int CTRL>
__device__ __forceinline__ float dpp_xadd(float v) {
  return v + __int_as_float(
      __builtin_amdgcn_update_dpp(0, __float_as_int(v), CTRL, 0xf, 0xf, true));
}
// full 16-lane sum: quad_perm[1,0,3,2]=0xB1, quad_perm[2,3,0,1]=0x4E,
// row_ror:4=0x124, row_ror:8=0x128  (HW-verified in R2)
__device__ __forceinline__ float row16_sum(float v) {
  v = dpp_xadd<0xB1>(v);
  v = dpp_xadd<0x4E>(v);
  v = dpp_xadd<0x124>(v);
  v = dpp_xadd<0x128>(v);
  return v;
}

// ---------------- Kernel 0: precompute l = lastm@W^T (fp32) and swizzled fp16 U ----
__global__ __launch_bounds__(256)
void precompute(const float* __restrict__ lastm, const float* __restrict__ W,
                const float* __restrict__ U,
                float* __restrict__ l_ws, _Float16* __restrict__ Uswz)
{
  const int t = threadIdx.x;
  if (blockIdx.x < NB) {
    const int b = blockIdx.x;
    __shared__ float lm_sm[NH];
    lm_sm[t] = lastm[(size_t)b * NH + t];
    __syncthreads();
    const float4* wrow = (const float4*)(W + (size_t)t * NH);
    const float4* lrow = (const float4*)lm_sm;
    float a0 = 0.f, a1 = 0.f, a2 = 0.f, a3 = 0.f;
#pragma unroll 8
    for (int i = 0; i < NH / 4; ++i) {
      float4 w4 = wrow[i];
      float4 m4 = lrow[i];
      a0 = fmaf(w4.x, m4.x, a0);
      a1 = fmaf(w4.y, m4.y, a1);
      a2 = fmaf(w4.z, m4.z, a2);
      a3 = fmaf(w4.w, m4.w, a3);
    }
    l_ws[(size_t)b * NH + t] = (a0 + a1) + (a2 + a3);
  } else {
    const int id    = (blockIdx.x - NB) * 256 + t;   // 8192 frags
    const int n_blk = id >> 9;
    const int kk    = (id >> 6) & 7;
    const int lane  = id & 63;
    const int row   = n_blk * 16 + (lane & 15);
    const int col   = kk * 32 + (lane >> 4) * 8;
    const float4* s = (const float4*)(U + (size_t)row * NH + col);
    const float4 a = s[0], c = s[1];
    f16x8 pk;
    pk[0] = (_Float16)a.x; pk[1] = (_Float16)a.y;
    pk[2] = (_Float16)a.z; pk[3] = (_Float16)a.w;
    pk[4] = (_Float16)c.x; pk[5] = (_Float16)c.y;
    pk[6] = (_Float16)c.z; pk[7] = (_Float16)c.w;
    *(f16x8*)(Uswz + (size_t)id * 8) = pk;
  }
}

#define CVT_HL(idx, val) { const float x_ = (val); const _Float16 h_ = (_Float16)x_; \
                           ph[idx] = h_; pl[idx] = (_Float16)(x_ - (float)h_); }

// ---------------- Kernel A: fully fused attention pool + projection per b -------
// grid 512 = one block per b (exactly 2 blocks/CU in ONE round — R11 proved any
// non-768-divisible grid growth pays a second ragged round), 512 threads =
// 8 waves x 32 n-cols. __launch_bounds__(512, 2): min-blocks-per-CU semantics
// (measured R2-R6); 128-reg cap, R10 used 80 with no spill.
// R8 lesson: hi/lo dual MFMA stream is the latency-hiding work — keep it.
// R10: no-max softmax (scores bounded |s|<~13 -> exp safe in fp32).
// R12: tail tile PEELED — main loop is 6 uniform 32-row tiles (no rows logic);
// tile 6 (8 valid rows) runs mt=0 only, no staging, no prefetch. Stale buf rows
// 8-15 produce finite garbage scores that t<8 guard zeroes (no NaN path through
// the tanh identity).
template<bool PRE>
__global__ __launch_bounds__(512, 2)
void fused_attn(const float* __restrict__ mem,    // [B,S,H]
                const float* __restrict__ lastm,  // [B,H]
                const float* __restrict__ U,      // [H,H] fp32 (fallback)
                const float* __restrict__ W,      // [H,H] (fallback)
                const float* __restrict__ V,      // [H]
                const float* __restrict__ l_ws,   // [B,H] (PRE)
                const _Float16* __restrict__ Uswz,// swizzled fp16 U (PRE)
                const float* __restrict__ MetaW,  // [4,H]
                const float* __restrict__ Metab,  // [4]
                float* __restrict__ out)          // [B,4]
{
  const int b = blockIdx.x;

  const int t     = threadIdx.x;   // 0..511
  const int wave  = t >> 6;        // 0..7: owns n-cols [wave*32, wave*32+32)
  const int lane  = t & 63;
  const int m16   = lane & 15;
  const int quad  = lane >> 4;
  const int g     = t >> 5;        // 0..15: pooled row-pair {2g, 2g+1}
  const int hblk  = (t & 31) * 8;  // pooled: 8 h-cols

  __shared__ __align__(16) _Float16 hi_sm[2][TILE_S][LDW];  // 33.8 KB
  __shared__ __align__(16) _Float16 lo_sm[2][TILE_S][LDW];  // 33.8 KB
  __shared__ float swave_sm[8][TILE_S];
  __shared__ float e_sm[TILE_S];
  __shared__ float z_sm[1];

  // per-thread l/V for this wave's 2 n-fragments
  float l_reg[2], v_reg[2];
  if constexpr (!PRE) {
    __shared__ float l_sm[NH];
    __shared__ float lm_sm[NH];
    if (t < NH) lm_sm[t] = lastm[(size_t)b * NH + t];
    __syncthreads();
    if (t < NH) {
      const float4* wrow = (const float4*)(W + (size_t)t * NH);
      const float4* lrow = (const float4*)lm_sm;
      float a0 = 0.f, a1 = 0.f, a2 = 0.f, a3 = 0.f;
#pragma unroll 8
      for (int i = 0; i < NH / 4; ++i) {
        float4 w4 = wrow[i];
        float4 m4 = lrow[i];
        a0 = fmaf(w4.x, m4.x, a0);
        a1 = fmaf(w4.y, m4.y, a1);
        a2 = fmaf(w4.z, m4.z, a2);
        a3 = fmaf(w4.w, m4.w, a3);
      }
      l_sm[t] = (a0 + a1) + (a2 + a3);
    }
    __syncthreads();
#pragma unroll
    for (int nf = 0; nf < 2; ++nf)
      l_reg[nf] = l_sm[wave * 32 + nf * 16 + m16];
  } else {
#pragma unroll
    for (int nf = 0; nf < 2; ++nf)
      l_reg[nf] = l_ws[(size_t)b * NH + wave * 32 + nf * 16 + m16];
  }
#pragma unroll
  for (int nf = 0; nf < 2; ++nf)
    v_reg[nf] = V[wave * 32 + nf * 16 + m16];
  const float vsum  = v_reg[0] + v_reg[1];
  const float vm2_0 = -2.f * v_reg[0];
  const float vm2_1 = -2.f * v_reg[1];

  // ---- U B-fragments in registers for the whole kernel: 2 nf x 8 kk = 64 VGPR ----
  f16x8 u_frag[2][8];
  if constexpr (PRE) {
    const _Float16* uw = Uswz + ((size_t)(wave * 2 * 8 * 64) + lane) * 8;
#pragma unroll
    for (int nf = 0; nf < 2; ++nf)
#pragma unroll
      for (int kk = 0; kk < 8; ++kk)
        u_frag[nf][kk] = *(const f16x8*)(uw + (size_t)((nf * 8 + kk) << 9));
  } else {
#pragma unroll
    for (int nf = 0; nf < 2; ++nf) {
      const int n = wave * 32 + nf * 16 + m16;
      const float* urow = U + (size_t)n * NH;
#pragma unroll
      for (int kk = 0; kk < 8; ++kk) {
        const float4 lo = *(const float4*)(urow + kk * 32 + quad * 8);
        const float4 hi = *(const float4*)(urow + kk * 32 + quad * 8 + 4);
        f16x8 f;
        f[0] = (_Float16)lo.x; f[1] = (_Float16)lo.y;
        f[2] = (_Float16)lo.z; f[3] = (_Float16)lo.w;
        f[4] = (_Float16)hi.x; f[5] = (_Float16)hi.y;
        f[6] = (_Float16)hi.z; f[7] = (_Float16)hi.w;
        u_frag[nf][kk] = f;
      }
    }
  }

  // ---- prologue: stage tile 0 into buffer 0; issue tile-1 loads into q regs ----
  float4 q00, q01, q10, q11;   // pending-tile prefetch (persists across iterations)
  {
    const float4* src4 = (const float4*)(mem + (size_t)b * NS * NH);
    const int f0 = t, f1 = 512 + t;
    const float4 a0 = src4[f0 * 2], a1 = src4[f0 * 2 + 1];
    const float4 b0 = src4[f1 * 2], b1 = src4[f1 * 2 + 1];
    {
      f16x8 ph, pl;
      CVT_HL(0, a0.x) CVT_HL(1, a0.y) CVT_HL(2, a0.z) CVT_HL(3, a0.w)
      CVT_HL(4, a1.x) CVT_HL(5, a1.y) CVT_HL(6, a1.z) CVT_HL(7, a1.w)
      *(f16x8*)&hi_sm[0][f0 >> 5][(f0 & 31) * 8] = ph;
      *(f16x8*)&lo_sm[0][f0 >> 5][(f0 & 31) * 8] = pl;
    }
    {
      f16x8 ph, pl;
      CVT_HL(0, b0.x) CVT_HL(1, b0.y) CVT_HL(2, b0.z) CVT_HL(3, b0.w)
      CVT_HL(4, b1.x) CVT_HL(5, b1.y) CVT_HL(6, b1.z) CVT_HL(7, b1.w)
      *(f16x8*)&hi_sm[0][f1 >> 5][(f1 & 31) * 8] = ph;
      *(f16x8*)&lo_sm[0][f1 >> 5][(f1 & 31) * 8] = pl;
    }
    // issue L(1) — tile 1 is always full (32 rows)
    const float4* nsrc = (const float4*)(mem + ((size_t)b * NS + TILE_S) * NH);
    q00 = nsrc[t * 2];         q01 = nsrc[t * 2 + 1];
    q10 = nsrc[(512 + t) * 2]; q11 = nsrc[(512 + t) * 2 + 1];
  }
  __syncthreads();

  float z_local = 0.f;   // lanes t<32: running sum of e over this lane's rows
  float pooledv[8];
#pragma unroll
  for (int j = 0; j < 8; ++j) pooledv[j] = 0.f;

  // ---- main loop: 6 uniform full tiles (rows 0..191) ----
  for (int tile = 0; tile < 6; ++tile) {
    const int cur = tile & 1;
    const int nxt = cur ^ 1;
    const int s0  = tile * TILE_S;
    const int rows_w = min(TILE_S, NS - (s0 + TILE_S));                          // 32, tile5: 8
    const int rows_i = (tile + 2 < 7) ? min(TILE_S, NS - (s0 + 2 * TILE_S)) : 0; // 32.., t4: 8, t5: 0

    // ---- MFMA: 32 rows x 32 n-cols per wave; hi+lo into same acc ----
    f32x4 acc[2][2];
    const f32x4 fzero = {0.f, 0.f, 0.f, 0.f};
#pragma unroll
    for (int mt = 0; mt < 2; ++mt)
#pragma unroll
      for (int nf = 0; nf < 2; ++nf)
        acc[mt][nf] = fzero;

#pragma unroll
    for (int kk = 0; kk < 8; ++kk) {
      const int c = kk * 32 + quad * 8;
      f16x8 a0h = *(const f16x8*)&hi_sm[cur][m16][c];
      f16x8 a1h = *(const f16x8*)&hi_sm[cur][16 + m16][c];
      f16x8 a0l = *(const f16x8*)&lo_sm[cur][m16][c];
      f16x8 a1l = *(const f16x8*)&lo_sm[cur][16 + m16][c];
#pragma unroll
      for (int nf = 0; nf < 2; ++nf) {
        acc[0][nf] = __builtin_amdgcn_mfma_f32_16x16x32_f16(a0h, u_frag[nf][kk], acc[0][nf], 0, 0, 0);
        acc[1][nf] = __builtin_amdgcn_mfma_f32_16x16x32_f16(a1h, u_frag[nf][kk], acc[1][nf], 0, 0, 0);
        acc[0][nf] = __builtin_amdgcn_mfma_f32_16x16x32_f16(a0l, u_frag[nf][kk], acc[0][nf], 0, 0, 0);
        acc[1][nf] = __builtin_amdgcn_mfma_f32_16x16x32_f16(a1l, u_frag[nf][kk], acc[1][nf], 0, 0, 0);
      }
    }

    // ---- p = vsum + sum_nf (-2 v[nf]) / (e^{2x}+1) (tanh identity), DPP n-reduce ----
#pragma unroll
    for (int mt = 0; mt < 2; ++mt) {
#pragma unroll
      for (int reg = 0; reg < 4; ++reg) {
        const float x0 = acc[mt][0][reg] + l_reg[0];
        const float x1 = acc[mt][1][reg] + l_reg[1];
        const float e0 = __expf(x0 + x0);
        const float e1 = __expf(x1 + x1);
        float s = vsum;
        s += __fdividef(vm2_0, e0 + 1.f);
        s += __fdividef(vm2_1, e1 + 1.f);
        s = row16_sum(s);
        if (m16 == 0)
          swave_sm[wave][mt * 16 + quad * 4 + reg] = s;
      }
    }
    __syncthreads();  // bar1: swave ready; current-tile MFMA LDS reads done

    // ---- lanes 0..31: e = exp(score) directly (all 32 rows valid) ----
    if (t < TILE_S) {
      float s = swave_sm[0][t];
#pragma unroll
      for (int w = 1; w < 8; ++w) s += swave_sm[w][t];
      const float e = __expf(s);
      e_sm[t] = e;
      z_local += e;
    }

    // ---- all waves: write pending tile (t+1) from q regs into buf[nxt] ----
    if ((t >> 5) < rows_w) {
      f16x8 ph, pl;
      CVT_HL(0, q00.x) CVT_HL(1, q00.y) CVT_HL(2, q00.z) CVT_HL(3, q00.w)
      CVT_HL(4, q01.x) CVT_HL(5, q01.y) CVT_HL(6, q01.z) CVT_HL(7, q01.w)
      *(f16x8*)&hi_sm[nxt][t >> 5][(t & 31) * 8] = ph;
      *(f16x8*)&lo_sm[nxt][t >> 5][(t & 31) * 8] = pl;
    }
    if (16 + (t >> 5) < rows_w) {
      f16x8 ph, pl;
      CVT_HL(0, q10.x) CVT_HL(1, q10.y) CVT_HL(2, q10.z) CVT_HL(3, q10.w)
      CVT_HL(4, q11.x) CVT_HL(5, q11.y) CVT_HL(6, q11.z) CVT_HL(7, q11.w)
      *(f16x8*)&hi_sm[nxt][16 + (t >> 5)][(t & 31) * 8] = ph;
      *(f16x8*)&lo_sm[nxt][16 + (t >> 5)][(t & 31) * 8] = pl;
    }

    // ---- issue loads for tile t+2 (consumed next tile) ----
    if (rows_i > 0) {
      const float4* nsrc = (const float4*)(mem + ((size_t)b * NS + s0 + 2 * TILE_S) * NH);
      if ((t >> 5) < rows_i)      { q00 = nsrc[t * 2];         q01 = nsrc[t * 2 + 1]; }
      if (16 + (t >> 5) < rows_i) { q10 = nsrc[(512 + t) * 2]; q11 = nsrc[(512 + t) * 2 + 1]; }
    }
    __syncthreads();  // bar2: e_sm ready; buf[nxt] staged

    // ---- pooled: thread owns 8 h-cols x 2 rows of hi_sm[cur]; no rescale.
    //      NO bar after: staging(t+1) writes buf[cur] only after bar1(t+1). ----
    const float e0 = e_sm[2 * g];
    const float e1 = e_sm[2 * g + 1];
    const f16x8 r0 = *(const f16x8*)&hi_sm[cur][2 * g][hblk];
    const f16x8 r1 = *(const f16x8*)&hi_sm[cur][2 * g + 1][hblk];
#pragma unroll
    for (int j = 0; j < 8; ++j)
      pooledv[j] = fmaf(e0, (float)r0[j], fmaf(e1, (float)r1[j], pooledv[j]));
  }

  // ---- peeled tail: tile 6, 8 valid rows in buf 0, mt=0 only, no staging ----
  {
    f32x4 acc[2];
    const f32x4 fzero = {0.f, 0.f, 0.f, 0.f};
    acc[0] = fzero; acc[1] = fzero;
#pragma unroll
    for (int kk = 0; kk < 8; ++kk) {
      const int c = kk * 32 + quad * 8;
      f16x8 a0h = *(const f16x8*)&hi_sm[0][m16][c];
      f16x8 a0l = *(const f16x8*)&lo_sm[0][m16][c];
#pragma unroll
      for (int nf = 0; nf < 2; ++nf) {
        acc[nf] = __builtin_amdgcn_mfma_f32_16x16x32_f16(a0h, u_frag[nf][kk], acc[nf], 0, 0, 0);
        acc[nf] = __builtin_amdgcn_mfma_f32_16x16x32_f16(a0l, u_frag[nf][kk], acc[nf], 0, 0, 0);
      }
    }
#pragma unroll
    for (int reg = 0; reg < 4; ++reg) {
      const float x0 = acc[0][reg] + l_reg[0];
      const float x1 = acc[1][reg] + l_reg[1];
      const float e0 = __expf(x0 + x0);
      const float e1 = __expf(x1 + x1);
      float s = vsum;
      s += __fdividef(vm2_0, e0 + 1.f);
      s += __fdividef(vm2_1, e1 + 1.f);
      s = row16_sum(s);
      if (m16 == 0)
        swave_sm[wave][quad * 4 + reg] = s;   // rows 0..15 only
    }
    __syncthreads();  // tail bar1

    if (t < TILE_S) {
      float e = 0.f;
      if (t < 8) {      // only 8 valid rows; swave rows 8..15 are garbage-but-finite
        float s = swave_sm[0][t];
#pragma unroll
        for (int w = 1; w < 8; ++w) s += swave_sm[w][t];
        e = __expf(s);
      }
      e_sm[t] = e;
      z_local += e;
    }
    __syncthreads();  // tail bar2: e_sm ready

    const float e0 = e_sm[2 * g];
    const float e1 = e_sm[2 * g + 1];
    const f16x8 r0 = *(const f16x8*)&hi_sm[0][2 * g][hblk];
    const f16x8 r1 = *(const f16x8*)&hi_sm[0][2 * g + 1][hblk];
#pragma unroll
    for (int j = 0; j < 8; ++j)
      pooledv[j] = fmaf(e0, (float)r0[j], fmaf(e1, (float)r1[j], pooledv[j]));
  }
  __syncthreads();  // final pooled reads done before scratch reuse

  // ---- epilogue: Z reduce (wave0), combine 16 replicas, normalize, project ----
  float* scratch   = (float*)&hi_sm[0][0][0];   // 16 x 264 f32 = 16896 B, fits
  float* pooled_sm = (float*)&lo_sm[0][0][0];   // 256 f32
  if (t < TILE_S) {
    float z = z_local;
#pragma unroll
    for (int off = 1; off < 32; off <<= 1)
      z += __shfl_xor(z, off);
    if (t == 0) z_sm[0] = z;
  }
  {
    f32x4 lo4 = {pooledv[0], pooledv[1], pooledv[2], pooledv[3]};
    f32x4 hi4 = {pooledv[4], pooledv[5], pooledv[6], pooledv[7]};
    *(f32x4*)&scratch[g * 264 + hblk]     = lo4;
    *(f32x4*)&scratch[g * 264 + hblk + 4] = hi4;
  }
  __syncthreads();
  const float Zi = 1.f / z_sm[0];
  if (t < NH) {
    float p = 0.f;
#pragma unroll
    for (int r = 0; r < 16; ++r)
      p += scratch[r * 264 + t];
    pooled_sm[t] = p * Zi;
  }
  __syncthreads();
  if (t < 256) {
    float s = 0.f;
#pragma unroll
    for (int i = 0; i < 4; ++i) {
      const int h = i * 64 + lane;
      s = fmaf(pooled_sm[h], MetaW[(size_t)wave * NH + h], s);
    }
#pragma unroll
    for (int off = 32; off > 0; off >>= 1)
      s += __shfl_down(s, off);
    if (lane == 0)
      out[b * 4 + wave] = s + Metab[wave];
  }
}

extern "C" void kernel_launch(void* const* d_in, const int* in_sizes, int n_in,
                              void* d_out, int out_size, void* d_ws, size_t ws_size,
                              hipStream_t stream) {
  const float* mem   = (const float*)d_in[0];
  const float* lastm = (const float*)d_in[1];
  const float* U     = (const float*)d_in[2];
  const float* W     = (const float*)d_in[3];
  const float* V     = (const float*)d_in[4];
  const float* MetaW = (const float*)d_in[5];
  const float* Metab = (const float*)d_in[6];
  float* out = (float*)d_out;
  float* ws  = (float*)d_ws;

  if (ws_size >= (size_t)WS_FLOATS_PRE * sizeof(float)) {
    float*    l_ws = ws + OFF_L;
    _Float16* Uswz = (_Float16*)(ws + OFF_UB);
    hipLaunchKernelGGL(precompute, dim3(NB + 32), dim3(256), 0, stream,
                       lastm, W, U, l_ws, Uswz);
    hipLaunchKernelGGL(fused_attn<true>, dim3(NB), dim3(512), 0, stream,
                       mem, lastm, U, W, V, l_ws, Uswz, MetaW, Metab, out);
  } else {
    hipLaunchKernelGGL(fused_attn<false>, dim3(NB), dim3(512), 0, stream,
                       mem, lastm, U, W, V, (const float*)nullptr, (const _Float16*)nullptr,
                       MetaW, Metab, out);
  }
}

// Round 13
// 192.217 us; speedup vs baseline: 1.0939x; 1.0076x over previous
//
#include <hip/hip_runtime.h>
#include <hip/hip_bf16.h>
#include <math.h>

#define NB 512
#define NS 200
#define NH 256
#define TILE_S 32

// ws float-offset layout (l + swizzled fp16 U only)
#define OFF_L    0                                 // l: 512*256 floats
#define OFF_UB   (NB * NH)                         // U-fp16 swizzled (32768 floats)
#define WS_FLOATS_PRE  (OFF_UB + (NH * NH) / 2)    // 655 KB

typedef _Float16 f16x8 __attribute__((ext_vector_type(8)));
typedef float    f32x4 __attribute__((ext_vector_type(4)));

// LDS tile layout: unpadded [32][256] f16 rows (512 B ≡ 0 mod 32 banks) with a
// 16B-unit XOR swizzle: unit' = unit ^ (row & 7). Rows 0..7 hit all 8 bank-slot
// positions exactly once (XOR permutes low 3 bits); rows 8..15 alias 2-way
// (free, m136). R10 measured 3.73M SQ_LDS_BANK_CONFLICT on the padded layout
// (~36% LDS-port overhead); this is the canonical fix. f16 column offset:
#define SWZ(r, u) ((((u) ^ ((r) & 7))) * 8)

// DPP-based add within each 16-lane row (VALU, not LDS port).
template<int CTRL>
__device__ __forceinline__ float dpp_xadd(float v) {
  return v + __int_as_float(
      __builtin_amdgcn_update_dpp(0, __float_as_int(v), CTRL, 0xf, 0xf, true));
}
// full 16-lane sum: quad_perm[1,0,3,2]=0xB1, quad_perm[2,3,0,1]=0x4E,
// row_ror:4=0x124, row_ror:8=0x128  (HW-verified in R2)
__device__ __forceinline__ float row16_sum(float v) {
  v = dpp_xadd<0xB1>(v);
  v = dpp_xadd<0x4E>(v);
  v = dpp_xadd<0x124>(v);
  v = dpp_xadd<0x128>(v);
  return v;
}

// ---------------- Kernel 0: precompute l = lastm@W^T (fp32) and swizzled fp16 U ----
__global__ __launch_bounds__(256)
void precompute(const float* __restrict__ lastm, const float* __restrict__ W,
                const float* __restrict__ U,
                float* __restrict__ l_ws, _Float16* __restrict__ Uswz)
{
  const int t = threadIdx.x;
  if (blockIdx.x < NB) {
    const int b = blockIdx.x;
    __shared__ float lm_sm[NH];
    lm_sm[t] = lastm[(size_t)b * NH + t];
    __syncthreads();
    const float4* wrow = (const float4*)(W + (size_t)t * NH);
    const float4* lrow = (const float4*)lm_sm;
    float a0 = 0.f, a1 = 0.f, a2 = 0.f, a3 = 0.f;
#pragma unroll 8
    for (int i = 0; i < NH / 4; ++i) {
      float4 w4 = wrow[i];
      float4 m4 = lrow[i];
      a0 = fmaf(w4.x, m4.x, a0);
      a1 = fmaf(w4.y, m4.y, a1);
      a2 = fmaf(w4.z, m4.z, a2);
      a3 = fmaf(w4.w, m4.w, a3);
    }
    l_ws[(size_t)b * NH + t] = (a0 + a1) + (a2 + a3);
  } else {
    const int id    = (blockIdx.x - NB) * 256 + t;   // 8192 frags
    const int n_blk = id >> 9;
    const int kk    = (id >> 6) & 7;
    const int lane  = id & 63;
    const int row   = n_blk * 16 + (lane & 15);
    const int col   = kk * 32 + (lane >> 4) * 8;
    const float4* s = (const float4*)(U + (size_t)row * NH + col);
    const float4 a = s[0], c = s[1];
    f16x8 pk;
    pk[0] = (_Float16)a.x; pk[1] = (_Float16)a.y;
    pk[2] = (_Float16)a.z; pk[3] = (_Float16)a.w;
    pk[4] = (_Float16)c.x; pk[5] = (_Float16)c.y;
    pk[6] = (_Float16)c.z; pk[7] = (_Float16)c.w;
    *(f16x8*)(Uswz + (size_t)id * 8) = pk;
  }
}

#define CVT_HL(idx, val) { const float x_ = (val); const _Float16 h_ = (_Float16)x_; \
                           ph[idx] = h_; pl[idx] = (_Float16)(x_ - (float)h_); }

// ---------------- Kernel A: fully fused attention pool + projection per b -------
// grid 512 = one block per b (exactly 2 blocks/CU in ONE round — R11 proved any
// non-768-divisible grid growth pays a second ragged round), 512 threads =
// 8 waves x 32 n-cols. __launch_bounds__(512, 2): min-blocks-per-CU semantics
// (measured R2-R6); 128-reg cap, R10 used 80 with no spill.
// R8: hi/lo dual MFMA stream is the latency-hiding work — keep it.
// R10: no-max softmax (scores bounded |s|<~13 -> exp safe in fp32).
// R12: tail tile peeled (6 uniform tiles + 8-row tail, mt=0 only, no staging).
// R13: XOR bank swizzle on the LDS tiles (see SWZ above).
template<bool PRE>
__global__ __launch_bounds__(512, 2)
void fused_attn(const float* __restrict__ mem,    // [B,S,H]
                const float* __restrict__ lastm,  // [B,H]
                const float* __restrict__ U,      // [H,H] fp32 (fallback)
                const float* __restrict__ W,      // [H,H] (fallback)
                const float* __restrict__ V,      // [H]
                const float* __restrict__ l_ws,   // [B,H] (PRE)
                const _Float16* __restrict__ Uswz,// swizzled fp16 U (PRE)
                const float* __restrict__ MetaW,  // [4,H]
                const float* __restrict__ Metab,  // [4]
                float* __restrict__ out)          // [B,4]
{
  const int b = blockIdx.x;

  const int t     = threadIdx.x;   // 0..511
  const int wave  = t >> 6;        // 0..7: owns n-cols [wave*32, wave*32+32)
  const int lane  = t & 63;
  const int m16   = lane & 15;
  const int quad  = lane >> 4;
  const int g     = t >> 5;        // 0..15: pooled row-pair {2g, 2g+1}
  const int u31   = t & 31;        // pooled / staging 16B-unit index

  __shared__ __align__(16) _Float16 hi_sm[2][TILE_S][NH];  // 32 KB
  __shared__ __align__(16) _Float16 lo_sm[2][TILE_S][NH];  // 32 KB
  __shared__ float swave_sm[8][TILE_S];
  __shared__ float e_sm[TILE_S];
  __shared__ float z_sm[1];

  // per-thread l/V for this wave's 2 n-fragments
  float l_reg[2], v_reg[2];
  if constexpr (!PRE) {
    __shared__ float l_sm[NH];
    __shared__ float lm_sm[NH];
    if (t < NH) lm_sm[t] = lastm[(size_t)b * NH + t];
    __syncthreads();
    if (t < NH) {
      const float4* wrow = (const float4*)(W + (size_t)t * NH);
      const float4* lrow = (const float4*)lm_sm;
      float a0 = 0.f, a1 = 0.f, a2 = 0.f, a3 = 0.f;
#pragma unroll 8
      for (int i = 0; i < NH / 4; ++i) {
        float4 w4 = wrow[i];
        float4 m4 = lrow[i];
        a0 = fmaf(w4.x, m4.x, a0);
        a1 = fmaf(w4.y, m4.y, a1);
        a2 = fmaf(w4.z, m4.z, a2);
        a3 = fmaf(w4.w, m4.w, a3);
      }
      l_sm[t] = (a0 + a1) + (a2 + a3);
    }
    __syncthreads();
#pragma unroll
    for (int nf = 0; nf < 2; ++nf)
      l_reg[nf] = l_sm[wave * 32 + nf * 16 + m16];
  } else {
#pragma unroll
    for (int nf = 0; nf < 2; ++nf)
      l_reg[nf] = l_ws[(size_t)b * NH + wave * 32 + nf * 16 + m16];
  }
#pragma unroll
  for (int nf = 0; nf < 2; ++nf)
    v_reg[nf] = V[wave * 32 + nf * 16 + m16];
  const float vsum  = v_reg[0] + v_reg[1];
  const float vm2_0 = -2.f * v_reg[0];
  const float vm2_1 = -2.f * v_reg[1];

  // ---- U B-fragments in registers for the whole kernel: 2 nf x 8 kk = 64 VGPR ----
  f16x8 u_frag[2][8];
  if constexpr (PRE) {
    const _Float16* uw = Uswz + ((size_t)(wave * 2 * 8 * 64) + lane) * 8;
#pragma unroll
    for (int nf = 0; nf < 2; ++nf)
#pragma unroll
      for (int kk = 0; kk < 8; ++kk)
        u_frag[nf][kk] = *(const f16x8*)(uw + (size_t)((nf * 8 + kk) << 9));
  } else {
#pragma unroll
    for (int nf = 0; nf < 2; ++nf) {
      const int n = wave * 32 + nf * 16 + m16;
      const float* urow = U + (size_t)n * NH;
#pragma unroll
      for (int kk = 0; kk < 8; ++kk) {
        const float4 lo = *(const float4*)(urow + kk * 32 + quad * 8);
        const float4 hi = *(const float4*)(urow + kk * 32 + quad * 8 + 4);
        f16x8 f;
        f[0] = (_Float16)lo.x; f[1] = (_Float16)lo.y;
        f[2] = (_Float16)lo.z; f[3] = (_Float16)lo.w;
        f[4] = (_Float16)hi.x; f[5] = (_Float16)hi.y;
        f[6] = (_Float16)hi.z; f[7] = (_Float16)hi.w;
        u_frag[nf][kk] = f;
      }
    }
  }

  // ---- prologue: stage tile 0 into buffer 0; issue tile-1 loads into q regs ----
  float4 q00, q01, q10, q11;   // pending-tile prefetch (persists across iterations)
  {
    const float4* src4 = (const float4*)(mem + (size_t)b * NS * NH);
    const int r0 = t >> 5, r1 = 16 + (t >> 5);
    const float4 a0 = src4[t * 2],         a1 = src4[t * 2 + 1];
    const float4 b0 = src4[(512 + t) * 2], b1 = src4[(512 + t) * 2 + 1];
    {
      f16x8 ph, pl;
      CVT_HL(0, a0.x) CVT_HL(1, a0.y) CVT_HL(2, a0.z) CVT_HL(3, a0.w)
      CVT_HL(4, a1.x) CVT_HL(5, a1.y) CVT_HL(6, a1.z) CVT_HL(7, a1.w)
      *(f16x8*)&hi_sm[0][r0][SWZ(r0, u31)] = ph;
      *(f16x8*)&lo_sm[0][r0][SWZ(r0, u31)] = pl;
    }
    {
      f16x8 ph, pl;
      CVT_HL(0, b0.x) CVT_HL(1, b0.y) CVT_HL(2, b0.z) CVT_HL(3, b0.w)
      CVT_HL(4, b1.x) CVT_HL(5, b1.y) CVT_HL(6, b1.z) CVT_HL(7, b1.w)
      *(f16x8*)&hi_sm[0][r1][SWZ(r1, u31)] = ph;
      *(f16x8*)&lo_sm[0][r1][SWZ(r1, u31)] = pl;
    }
    // issue L(1) — tile 1 is always full (32 rows)
    const float4* nsrc = (const float4*)(mem + ((size_t)b * NS + TILE_S) * NH);
    q00 = nsrc[t * 2];         q01 = nsrc[t * 2 + 1];
    q10 = nsrc[(512 + t) * 2]; q11 = nsrc[(512 + t) * 2 + 1];
  }
  __syncthreads();

  float z_local = 0.f;   // lanes t<32: running sum of e over this lane's rows
  float pooledv[8];
#pragma unroll
  for (int j = 0; j < 8; ++j) pooledv[j] = 0.f;

  // ---- main loop: 6 uniform full tiles (rows 0..191) ----
  for (int tile = 0; tile < 6; ++tile) {
    const int cur = tile & 1;
    const int nxt = cur ^ 1;
    const int s0  = tile * TILE_S;
    const int rows_w = min(TILE_S, NS - (s0 + TILE_S));                          // 32, tile5: 8
    const int rows_i = (tile + 2 < 7) ? min(TILE_S, NS - (s0 + 2 * TILE_S)) : 0; // 32.., t4: 8, t5: 0

    // ---- MFMA: 32 rows x 32 n-cols per wave; hi+lo into same acc ----
    f32x4 acc[2][2];
    const f32x4 fzero = {0.f, 0.f, 0.f, 0.f};
#pragma unroll
    for (int mt = 0; mt < 2; ++mt)
#pragma unroll
      for (int nf = 0; nf < 2; ++nf)
        acc[mt][nf] = fzero;

#pragma unroll
    for (int kk = 0; kk < 8; ++kk) {
      // rows m16 and 16+m16 share (row&7) -> same swizzled column
      const int c = SWZ(m16, kk * 4 + quad);
      f16x8 a0h = *(const f16x8*)&hi_sm[cur][m16][c];
      f16x8 a1h = *(const f16x8*)&hi_sm[cur][16 + m16][c];
      f16x8 a0l = *(const f16x8*)&lo_sm[cur][m16][c];
      f16x8 a1l = *(const f16x8*)&lo_sm[cur][16 + m16][c];
#pragma unroll
      for (int nf = 0; nf < 2; ++nf) {
        acc[0][nf] = __builtin_amdgcn_mfma_f32_16x16x32_f16(a0h, u_frag[nf][kk], acc[0][nf], 0, 0, 0);
        acc[1][nf] = __builtin_amdgcn_mfma_f32_16x16x32_f16(a1h, u_frag[nf][kk], acc[1][nf], 0, 0, 0);
        acc[0][nf] = __builtin_amdgcn_mfma_f32_16x16x32_f16(a0l, u_frag[nf][kk], acc[0][nf], 0, 0, 0);
        acc[1][nf] = __builtin_amdgcn_mfma_f32_16x16x32_f16(a1l, u_frag[nf][kk], acc[1][nf], 0, 0, 0);
      }
    }

    // ---- p = vsum + sum_nf (-2 v[nf]) / (e^{2x}+1) (tanh identity), DPP n-reduce ----
#pragma unroll
    for (int mt = 0; mt < 2; ++mt) {
#pragma unroll
      for (int reg = 0; reg < 4; ++reg) {
        const float x0 = acc[mt][0][reg] + l_reg[0];
        const float x1 = acc[mt][1][reg] + l_reg[1];
        const float e0 = __expf(x0 + x0);
        const float e1 = __expf(x1 + x1);
        float s = vsum;
        s += __fdividef(vm2_0, e0 + 1.f);
        s += __fdividef(vm2_1, e1 + 1.f);
        s = row16_sum(s);
        if (m16 == 0)
          swave_sm[wave][mt * 16 + quad * 4 + reg] = s;
      }
    }
    __syncthreads();  // bar1: swave ready; current-tile MFMA LDS reads done

    // ---- lanes 0..31: e = exp(score) directly (all 32 rows valid) ----
    if (t < TILE_S) {
      float s = swave_sm[0][t];
#pragma unroll
      for (int w = 1; w < 8; ++w) s += swave_sm[w][t];
      const float e = __expf(s);
      e_sm[t] = e;
      z_local += e;
    }

    // ---- all waves: write pending tile (t+1) from q regs into buf[nxt] ----
    if ((t >> 5) < rows_w) {
      const int r = t >> 5;
      f16x8 ph, pl;
      CVT_HL(0, q00.x) CVT_HL(1, q00.y) CVT_HL(2, q00.z) CVT_HL(3, q00.w)
      CVT_HL(4, q01.x) CVT_HL(5, q01.y) CVT_HL(6, q01.z) CVT_HL(7, q01.w)
      *(f16x8*)&hi_sm[nxt][r][SWZ(r, u31)] = ph;
      *(f16x8*)&lo_sm[nxt][r][SWZ(r, u31)] = pl;
    }
    if (16 + (t >> 5) < rows_w) {
      const int r = 16 + (t >> 5);
      f16x8 ph, pl;
      CVT_HL(0, q10.x) CVT_HL(1, q10.y) CVT_HL(2, q10.z) CVT_HL(3, q10.w)
      CVT_HL(4, q11.x) CVT_HL(5, q11.y) CVT_HL(6, q11.z) CVT_HL(7, q11.w)
      *(f16x8*)&hi_sm[nxt][r][SWZ(r, u31)] = ph;
      *(f16x8*)&lo_sm[nxt][r][SWZ(r, u31)] = pl;
    }

    // ---- issue loads for tile t+2 (consumed next tile) ----
    if (rows_i > 0) {
      const float4* nsrc = (const float4*)(mem + ((size_t)b * NS + s0 + 2 * TILE_S) * NH);
      if ((t >> 5) < rows_i)      { q00 = nsrc[t * 2];         q01 = nsrc[t * 2 + 1]; }
      if (16 + (t >> 5) < rows_i) { q10 = nsrc[(512 + t) * 2]; q11 = nsrc[(512 + t) * 2 + 1]; }
    }
    __syncthreads();  // bar2: e_sm ready; buf[nxt] staged

    // ---- pooled: thread owns 8 h-cols x 2 rows of hi_sm[cur]; no rescale.
    //      NO bar after: staging(t+1) writes buf[cur] only after bar1(t+1). ----
    const float e0 = e_sm[2 * g];
    const float e1 = e_sm[2 * g + 1];
    const f16x8 r0 = *(const f16x8*)&hi_sm[cur][2 * g][SWZ(2 * g, u31)];
    const f16x8 r1 = *(const f16x8*)&hi_sm[cur][2 * g + 1][SWZ(2 * g + 1, u31)];
#pragma unroll
    for (int j = 0; j < 8; ++j)
      pooledv[j] = fmaf(e0, (float)r0[j], fmaf(e1, (float)r1[j], pooledv[j]));
  }

  // ---- peeled tail: tile 6, 8 valid rows in buf 0, mt=0 only, no staging ----
  {
    f32x4 acc[2];
    const f32x4 fzero = {0.f, 0.f, 0.f, 0.f};
    acc[0] = fzero; acc[1] = fzero;
#pragma unroll
    for (int kk = 0; kk < 8; ++kk) {
      const int c = SWZ(m16, kk * 4 + quad);
      f16x8 a0h = *(const f16x8*)&hi_sm[0][m16][c];
      f16x8 a0l = *(const f16x8*)&lo_sm[0][m16][c];
#pragma unroll
      for (int nf = 0; nf < 2; ++nf) {
        acc[nf] = __builtin_amdgcn_mfma_f32_16x16x32_f16(a0h, u_frag[nf][kk], acc[nf], 0, 0, 0);
        acc[nf] = __builtin_amdgcn_mfma_f32_16x16x32_f16(a0l, u_frag[nf][kk], acc[nf], 0, 0, 0);
      }
    }
#pragma unroll
    for (int reg = 0; reg < 4; ++reg) {
      const float x0 = acc[0][reg] + l_reg[0];
      const float x1 = acc[1][reg] + l_reg[1];
      const float e0 = __expf(x0 + x0);
      const float e1 = __expf(x1 + x1);
      float s = vsum;
      s += __fdividef(vm2_0, e0 + 1.f);
      s += __fdividef(vm2_1, e1 + 1.f);
      s = row16_sum(s);
      if (m16 == 0)
        swave_sm[wave][quad * 4 + reg] = s;   // rows 0..15 only
    }
    __syncthreads();  // tail bar1

    if (t < TILE_S) {
      float e = 0.f;
      if (t < 8) {      // only 8 valid rows; swave rows 8..15 are garbage-but-finite
        float s = swave_sm[0][t];
#pragma unroll
        for (int w = 1; w < 8; ++w) s += swave_sm[w][t];
        e = __expf(s);
      }
      e_sm[t] = e;
      z_local += e;
    }
    __syncthreads();  // tail bar2: e_sm ready

    const float e0 = e_sm[2 * g];
    const float e1 = e_sm[2 * g + 1];
    const f16x8 r0 = *(const f16x8*)&hi_sm[0][2 * g][SWZ(2 * g, u31)];
    const f16x8 r1 = *(const f16x8*)&hi_sm[0][2 * g + 1][SWZ(2 * g + 1, u31)];
#pragma unroll
    for (int j = 0; j < 8; ++j)
      pooledv[j] = fmaf(e0, (float)r0[j], fmaf(e1, (float)r1[j], pooledv[j]));
  }
  __syncthreads();  // final pooled reads done before scratch reuse

  // ---- epilogue: Z reduce (wave0), combine 16 replicas, normalize, project ----
  float* scratch   = (float*)&hi_sm[0][0][0];   // 16 x 264 f32 = 16.9 KB <= 32 KB hi region
  float* pooled_sm = (float*)&lo_sm[0][0][0];   // 256 f32
  if (t < TILE_S) {
    float z = z_local;
#pragma unroll
    for (int off = 1; off < 32; off <<= 1)
      z += __shfl_xor(z, off);
    if (t == 0) z_sm[0] = z;
  }
  {
    const int hblk = u31 * 8;
    f32x4 lo4 = {pooledv[0], pooledv[1], pooledv[2], pooledv[3]};
    f32x4 hi4 = {pooledv[4], pooledv[5], pooledv[6], pooledv[7]};
    *(f32x4*)&scratch[g * 264 + hblk]     = lo4;
    *(f32x4*)&scratch[g * 264 + hblk + 4] = hi4;
  }
  __syncthreads();
  const float Zi = 1.f / z_sm[0];
  if (t < NH) {
    float p = 0.f;
#pragma unroll
    for (int r = 0; r < 16; ++r)
      p += scratch[r * 264 + t];
    pooled_sm[t] = p * Zi;
  }
  __syncthreads();
  if (t < 256) {
    float s = 0.f;
#pragma unroll
    for (int i = 0; i < 4; ++i) {
      const int h = i * 64 + lane;
      s = fmaf(pooled_sm[h], MetaW[(size_t)wave * NH + h], s);
    }
#pragma unroll
    for (int off = 32; off > 0; off >>= 1)
      s += __shfl_down(s, off);
    if (lane == 0)
      out[b * 4 + wave] = s + Metab[wave];
  }
}

extern "C" void kernel_launch(void* const* d_in, const int* in_sizes, int n_in,
                              void* d_out, int out_size, void* d_ws, size_t ws_size,
                              hipStream_t stream) {
  const float* mem   = (const float*)d_in[0];
  const float* lastm = (const float*)d_in[1];
  const float* U     = (const float*)d_in[2];
  const float* W     = (const float*)d_in[3];
  const float* V     = (const float*)d_in[4];
  const float* MetaW = (const float*)d_in[5];
  const float* Metab = (const float*)d_in[6];
  float* out = (float*)d_out;
  float* ws  = (float*)d_ws;

  if (ws_size >= (size_t)WS_FLOATS_PRE * sizeof(float)) {
    float*    l_ws = ws + OFF_L;
    _Float16* Uswz = (_Float16*)(ws + OFF_UB);
    hipLaunchKernelGGL(precompute, dim3(NB + 32), dim3(256), 0, stream,
                       lastm, W, U, l_ws, Uswz);
    hipLaunchKernelGGL(fused_attn<true>, dim3(NB), dim3(512), 0, stream,
                       mem, lastm, U, W, V, l_ws, Uswz, MetaW, Metab, out);
  } else {
    hipLaunchKernelGGL(fused_attn<false>, dim3(NB), dim3(512), 0, stream,
                       mem, lastm, U, W, V, (const float*)nullptr, (const _Float16*)nullptr,
                       MetaW, Metab, out);
  }
}